// Round 3
// baseline (492.863 us; speedup 1.0000x reference)
//
#include <hip/hip_runtime.h>
#include <hip/hip_bf16.h>

#define T_LEN 4096
#define EMB   1024
#define NHEADS 8
#define HDIM  128
#define QSCALE 0.12752039955379307f   // (1/sqrt(128)) * log2(e) -- folded into Q

typedef __attribute__((ext_vector_type(8))) short bf16x8;
typedef __attribute__((ext_vector_type(4))) short s16x4;
typedef __attribute__((ext_vector_type(4))) float f32x4;

__device__ __forceinline__ short f2bf(float f) {
    unsigned u = __builtin_bit_cast(unsigned, f);
    u += 0x7fffu + ((u >> 16) & 1u);   // RNE
    return (short)(u >> 16);
}

__device__ __forceinline__ unsigned cvt_pk_bf16(float lo, float hi) {
    unsigned r;
    asm("v_cvt_pk_bf16_f32 %0, %1, %2" : "=v"(r) : "v"(lo), "v"(hi));
    return r;
}

// ---------------- PE table: pe[t][2i]=sin(t*f_i), pe[t][2i+1]=cos(t*f_i) ----------------
__global__ void pe_kernel(float* __restrict__ pe) {
    int idx = blockIdx.x * 256 + threadIdx.x;           // 4096*64 pairs
    if (idx >= T_LEN * 64) return;
    int t = idx >> 6, i = idx & 63;
    float f = expf(-9.210340371976184f * (float)i / 64.0f);
    float a = (float)t * f;
    pe[t * HDIM + 2 * i]     = sinf(a);
    pe[t * HDIM + 2 * i + 1] = cosf(a);
}

// ---------------- f32 -> bf16 convert (4 elems/thread), row-major copy ----------------
__global__ void cvt_kernel(const float* __restrict__ src, short* __restrict__ dst, int n) {
    int e0 = (blockIdx.x * 256 + threadIdx.x) * 4;
    if (e0 >= n) return;
    f32x4 v = *(const f32x4*)(src + e0);
    s16x4 o;
    for (int j = 0; j < 4; ++j) o[j] = f2bf(v[j]);
    *(s16x4*)(dst + e0) = o;
}

// ---------------- f32 [R][C] -> bf16 [C][R] transpose (32x32 LDS tiles) ----------------
__global__ __launch_bounds__(256)
void transpose_cvt_kernel(const float* __restrict__ src, short* __restrict__ dst,
                          int R, int C) {
    __shared__ short t[32][33];
    const int r0 = blockIdx.x * 32, c0 = blockIdx.y * 32;
    const int tr = threadIdx.x >> 3, tc4 = (threadIdx.x & 7) * 4;
    f32x4 v = *(const f32x4*)(src + (long)(r0 + tr) * C + c0 + tc4);
    for (int j = 0; j < 4; ++j) t[tc4 + j][tr] = f2bf(v[j]);
    __syncthreads();
    s16x4 o;
    for (int j = 0; j < 4; ++j) o[j] = t[tr][tc4 + j];
    *(s16x4*)(dst + (long)(c0 + tr) * R + r0 + tc4) = o;
}

// ---------------- LDS-free bf16 MFMA GEMM: 64x128 tile, 4 waves (2m x 2n), K=1024 ----------------
// Both operands row-major-in-K (A [M][1024], Bt [N][1024]); fragments are direct
// 16B/lane global loads (L1/L2-served; no LDS, no barriers -> free compiler pipelining).
// MODE 0: proj  C = x@[Wq|Wkv], epilogue: +bias +pe (Q also *QSCALE), split-store Q/K/Vt
// MODE 1: out   C = attn@Wo -> fp32 d_out
template<int MODE>
__global__ __launch_bounds__(256)
void gemm_kernel(const short* __restrict__ A, const short* __restrict__ Bt,
                 const float* __restrict__ bq, const float* __restrict__ bkv,
                 const float* __restrict__ pe,
                 short* __restrict__ Qb, short* __restrict__ Kb, short* __restrict__ Vtb,
                 float* __restrict__ Cout) {
    const int lane = threadIdx.x & 63;
    const int wid  = threadIdx.x >> 6;
    const int l15 = lane & 15, lk = lane >> 4;
    const int m0 = blockIdx.x * 64 + (wid >> 1) * 32;
    const int n0 = blockIdx.y * 128 + (wid & 1) * 64;

    const short* Ap = A  + (long)(m0 + l15) * 1024 + lk * 8;
    const short* Bp = Bt + (long)(n0 + l15) * 1024 + lk * 8;

    f32x4 acc[2][4] = {};
#pragma unroll 4
    for (int k0 = 0; k0 < 1024; k0 += 32) {
        bf16x8 a0 = *(const bf16x8*)(Ap + k0);
        bf16x8 a1 = *(const bf16x8*)(Ap + 16 * 1024 + k0);
        bf16x8 b0 = *(const bf16x8*)(Bp + k0);
        bf16x8 b1 = *(const bf16x8*)(Bp + 16 * 1024 + k0);
        bf16x8 b2 = *(const bf16x8*)(Bp + 32 * 1024 + k0);
        bf16x8 b3 = *(const bf16x8*)(Bp + 48 * 1024 + k0);
        acc[0][0] = __builtin_amdgcn_mfma_f32_16x16x32_bf16(a0, b0, acc[0][0], 0, 0, 0);
        acc[0][1] = __builtin_amdgcn_mfma_f32_16x16x32_bf16(a0, b1, acc[0][1], 0, 0, 0);
        acc[0][2] = __builtin_amdgcn_mfma_f32_16x16x32_bf16(a0, b2, acc[0][2], 0, 0, 0);
        acc[0][3] = __builtin_amdgcn_mfma_f32_16x16x32_bf16(a0, b3, acc[0][3], 0, 0, 0);
        acc[1][0] = __builtin_amdgcn_mfma_f32_16x16x32_bf16(a1, b0, acc[1][0], 0, 0, 0);
        acc[1][1] = __builtin_amdgcn_mfma_f32_16x16x32_bf16(a1, b1, acc[1][1], 0, 0, 0);
        acc[1][2] = __builtin_amdgcn_mfma_f32_16x16x32_bf16(a1, b2, acc[1][2], 0, 0, 0);
        acc[1][3] = __builtin_amdgcn_mfma_f32_16x16x32_bf16(a1, b3, acc[1][3], 0, 0, 0);
    }

    // epilogue; C/D layout: col = lane&15, row = (lane>>4)*4 + r
#pragma unroll
    for (int mi = 0; mi < 2; ++mi)
#pragma unroll
        for (int ni = 0; ni < 4; ++ni)
#pragma unroll
            for (int r = 0; r < 4; ++r) {
                int row = m0 + mi * 16 + lk * 4 + r;
                int col = n0 + ni * 16 + l15;
                float v = acc[mi][ni][r];
                if (MODE == 0) {
                    if (col < 1024) {            // Q: (+bq +pe) * QSCALE (base-2 softmax domain)
                        v = (v + bq[col] + pe[row * HDIM + (col & 127)]) * QSCALE;
                        Qb[(long)row * 1024 + col] = f2bf(v);
                    } else if (col < 1152) {     // K: +bkv[0:128] +pe
                        int d = col - 1024;
                        v += bkv[d] + pe[row * HDIM + d];
                        Kb[row * HDIM + d] = f2bf(v);
                    } else {                     // V: +bkv[128:256], store transposed [d][t]
                        v += bkv[col - 1024];
                        Vtb[(long)(col - 1152) * T_LEN + row] = f2bf(v);
                    }
                } else {
                    Cout[(long)row * 1024 + col] = v;
                }
            }
}

// ---------------- flash attention v3: no K/V staging, no barriers ----------------
// K (1 MiB) and V^T (1 MiB) are L1/L2-resident; all 4 waves of a block read identical
// fragments -> direct 16B/lane global loads. Waves fully independent (no __syncthreads).
// Swapped QK^T (lane-local softmax, exp2 domain), P via wave-private LDS (144B stride:
// b128 reads conflict-free, b64 stores 2-way).
__global__ __launch_bounds__(256, 2)
void attn_kernel(const short* __restrict__ Qb, const short* __restrict__ Kb,
                 const short* __restrict__ Vtb, short* __restrict__ Ob) {
    const int tid = threadIdx.x, lane = tid & 63, w = tid >> 6;
    const int l15 = lane & 15, lk = lane >> 4;
    const int qt = 63 - (blockIdx.x >> 3);        // descending length: long blocks first
    const int h  = blockIdx.x & 7;
    const int qw = qt * 64 + w * 16;
    const int nkt = qt + 1;

    __shared__ __align__(16) char Ps[4][16 * 144];   // per-wave P [16 q][64 k] bf16, stride 144B

    // Q fragments (B-operand: lane l15 = query col, k = lk*8+j). Pre-scaled by QSCALE.
    bf16x8 qa[4];
#pragma unroll
    for (int kc = 0; kc < 4; ++kc)
        qa[kc] = *(const bf16x8*)(Qb + (long)(qw + l15) * 1024 + h * HDIM + kc * 32 + lk * 8);

    const short* Kp = Kb  + l15 * HDIM + lk * 8;       // + (kbase+ct*16)*HDIM
    const short* Vp = Vtb + (long)l15 * T_LEN + lk * 8; // + dt*16*T_LEN + kbase (+32)

    f32x4 o[8] = {};
    float m2 = -INFINITY, lsum = 0.f;   // per-lane: lane owns query l15

    for (int kt = 0; kt < nkt; ++kt) {
        const int kbase = kt * 64;

        // S^T = K @ Q^T : D[key_local][query], col = l15 = query, row = lk*4+r = key_local
        f32x4 S[4];
        __builtin_amdgcn_s_setprio(1);
#pragma unroll
        for (int ct = 0; ct < 4; ++ct) {
            f32x4 s = {};
#pragma unroll
            for (int kc = 0; kc < 4; ++kc) {
                bf16x8 a = *(const bf16x8*)(Kp + (long)(kbase + ct * 16) * HDIM + kc * 32);
                s = __builtin_amdgcn_mfma_f32_16x16x32_bf16(a, qa[kc], s, 0, 0, 0);
            }
            S[ct] = s;
        }
        __builtin_amdgcn_s_setprio(0);

        if (kt == nkt - 1) {   // causal mask: only the diagonal tile
            const int query = qw + l15;
#pragma unroll
            for (int ct = 0; ct < 4; ++ct)
#pragma unroll
                for (int r = 0; r < 4; ++r)
                    if (kbase + ct * 16 + lk * 4 + r > query) S[ct][r] = -1e30f;
        }

        // lane-local softmax (base-2); 2+2 shfl_xor across the 4 lanes sharing query l15
        f32x4 mx4;
#pragma unroll
        for (int j = 0; j < 4; ++j)
            mx4[j] = fmaxf(fmaxf(S[0][j], S[1][j]), fmaxf(S[2][j], S[3][j]));
        float tm = fmaxf(fmaxf(mx4[0], mx4[1]), fmaxf(mx4[2], mx4[3]));
        tm = fmaxf(tm, __shfl_xor(tm, 16));
        tm = fmaxf(tm, __shfl_xor(tm, 32));
        float nm = fmaxf(m2, tm);
        float sc = __builtin_amdgcn_exp2f(m2 - nm);
        m2 = nm;
        f32x4 ps4 = {};
#pragma unroll
        for (int ct = 0; ct < 4; ++ct) {
#pragma unroll
            for (int j = 0; j < 4; ++j)
                S[ct][j] = __builtin_amdgcn_exp2f(S[ct][j] - nm);
            ps4 += S[ct];
        }
        float ps = (ps4[0] + ps4[1]) + (ps4[2] + ps4[3]);
        ps += __shfl_xor(ps, 16);
        ps += __shfl_xor(ps, 32);
        lsum = lsum * sc + ps;

        // P -> bf16, b64 stores into wave-private LDS (row stride 144B)
#pragma unroll
        for (int ct = 0; ct < 4; ++ct) {
            uint2 pk;
            pk.x = cvt_pk_bf16(S[ct][0], S[ct][1]);
            pk.y = cvt_pk_bf16(S[ct][2], S[ct][3]);
            *(uint2*)(Ps[w] + l15 * 144 + ct * 32 + lk * 8) = pk;
        }

        // rescale O (rows = query lk*4+r): fetch per-row sc from owning lanes
        f32x4 scq;
#pragma unroll
        for (int r = 0; r < 4; ++r) scq[r] = __shfl(sc, lk * 4 + r);
#pragma unroll
        for (int dt = 0; dt < 8; ++dt) o[dt] *= scq;

        // O += P @ V  (A = P from LDS, B = V^T fragments direct from global)
        bf16x8 pa0 = *(const bf16x8*)(Ps[w] + l15 * 144 + lk * 16);
        bf16x8 pa1 = *(const bf16x8*)(Ps[w] + l15 * 144 + 64 + lk * 16);
        __builtin_amdgcn_s_setprio(1);
#pragma unroll
        for (int dt = 0; dt < 8; ++dt) {
            bf16x8 vb0 = *(const bf16x8*)(Vp + (long)(dt * 16) * T_LEN + kbase);
            o[dt] = __builtin_amdgcn_mfma_f32_16x16x32_bf16(pa0, vb0, o[dt], 0, 0, 0);
            bf16x8 vb1 = *(const bf16x8*)(Vp + (long)(dt * 16) * T_LEN + kbase + 32);
            o[dt] = __builtin_amdgcn_mfma_f32_16x16x32_bf16(pa1, vb1, o[dt], 0, 0, 0);
        }
        __builtin_amdgcn_s_setprio(0);
    }

    // epilogue: attn (bf16) row-major [T][H*D]
    f32x4 lq, rl;
#pragma unroll
    for (int r = 0; r < 4; ++r) lq[r] = __shfl(lsum, lk * 4 + r);
#pragma unroll
    for (int r = 0; r < 4; ++r) rl[r] = 1.0f / lq[r];
#pragma unroll
    for (int dt = 0; dt < 8; ++dt)
#pragma unroll
        for (int r = 0; r < 4; ++r) {
            int row = qw + lk * 4 + r;
            int col = h * HDIM + dt * 16 + l15;
            Ob[(long)row * 1024 + col] = f2bf(o[dt][r] * rl[r]);
        }
}

extern "C" void kernel_launch(void* const* d_in, const int* in_sizes, int n_in,
                              void* d_out, int out_size, void* d_ws, size_t ws_size,
                              hipStream_t stream) {
    const float* x   = (const float*)d_in[0];
    const float* Wq  = (const float*)d_in[1];
    const float* bq  = (const float*)d_in[2];
    const float* Wkv = (const float*)d_in[3];
    const float* bkv = (const float*)d_in[4];
    const float* Wo  = (const float*)d_in[5];
    float* out = (float*)d_out;
    char* ws = (char*)d_ws;

    float* pe  = (float*)(ws);                        // 4096*128*4  = 2 MiB
    short* xb  = (short*)(ws + (2l  << 20));          // 4096*1024*2 = 8 MiB
    short* wt  = (short*)(ws + (10l << 20));          // 1280*1024*2 = 2.5 MiB  (W^T: [n][k])
    short* wot = (short*)(ws + (13l << 20));          // 1024*1024*2 = 2 MiB    (Wo^T)
    short* Qb  = (short*)(ws + (15l << 20));          // 4096*1024*2 = 8 MiB
    short* Kb  = (short*)(ws + (23l << 20));          // 4096*128*2  = 1 MiB
    short* Vtb = (short*)(ws + (24l << 20));          // 128*4096*2  = 1 MiB
    short* Ab  = (short*)(ws + (25l << 20));          // 4096*1024*2 = 8 MiB

    pe_kernel<<<1024, 256, 0, stream>>>(pe);
    cvt_kernel<<<4096, 256, 0, stream>>>(x, xb, T_LEN * EMB);
    transpose_cvt_kernel<<<dim3(32, 32), 256, 0, stream>>>(Wq,  wt,                EMB, 1024);
    transpose_cvt_kernel<<<dim3(32, 8),  256, 0, stream>>>(Wkv, wt + 1024 * 1024,  EMB, 256);
    transpose_cvt_kernel<<<dim3(32, 32), 256, 0, stream>>>(Wo,  wot,               EMB, 1024);

    gemm_kernel<0><<<dim3(64, 10), 256, 0, stream>>>(xb, wt, bq, bkv, pe,
                                                     Qb, Kb, Vtb, nullptr);
    attn_kernel<<<512, 256, 0, stream>>>(Qb, Kb, Vtb, Ab);
    gemm_kernel<1><<<dim3(64, 8), 256, 0, stream>>>(Ab, wot, nullptr, nullptr, nullptr,
                                                    nullptr, nullptr, nullptr, out);
}

// Round 5
// 186.710 us; speedup vs baseline: 2.6397x; 2.6397x over previous
//
#include <hip/hip_runtime.h>
#include <hip/hip_bf16.h>

#define T_LEN 4096
#define EMB   1024
#define HDIM  128
#define QSCALE 0.12752039955379307f   // (1/sqrt(128)) * log2(e) -- folded into Q

typedef __attribute__((ext_vector_type(8))) short bf16x8;
typedef __attribute__((ext_vector_type(4))) short s16x4;
typedef __attribute__((ext_vector_type(4))) float f32x4;
typedef __attribute__((ext_vector_type(2))) unsigned u32x2;

__device__ __forceinline__ short f2bf(float f) {
    unsigned u = __builtin_bit_cast(unsigned, f);
    u += 0x7fffu + ((u >> 16) & 1u);   // RNE
    return (short)(u >> 16);
}

__device__ __forceinline__ unsigned cvt_pk_bf16(float lo, float hi) {
    unsigned r;
    asm("v_cvt_pk_bf16_f32 %0, %1, %2" : "=v"(r) : "v"(lo), "v"(hi));
    return r;
}

// PV MFMA: K=16 so the A-operand (4 bf16/lane, k=lk*4+j) matches swapped-QK^T's
// S layout exactly -> P stays in registers, no LDS round-trip.
#if __has_builtin(__builtin_amdgcn_mfma_f32_16x16x16bf16_1k)
__device__ __forceinline__ f32x4 mfma16(s16x4 a, s16x4 b, f32x4 c) {
    return __builtin_amdgcn_mfma_f32_16x16x16bf16_1k(a, b, c, 0, 0, 0);
}
#else
__device__ __forceinline__ f32x4 mfma16(s16x4 a, s16x4 b, f32x4 c) {
    bf16x8 a8 = {a[0], a[1], a[2], a[3], 0, 0, 0, 0};
    bf16x8 b8 = {b[0], b[1], b[2], b[3], 0, 0, 0, 0};
    return __builtin_amdgcn_mfma_f32_16x16x32_bf16(a8, b8, c, 0, 0, 0);
}
#endif

// ---------------- PE table ----------------
__global__ void pe_kernel(float* __restrict__ pe) {
    int idx = blockIdx.x * 256 + threadIdx.x;
    if (idx >= T_LEN * 64) return;
    int t = idx >> 6, i = idx & 63;
    float f = expf(-9.210340371976184f * (float)i / 64.0f);
    float a = (float)t * f;
    pe[t * HDIM + 2 * i]     = sinf(a);
    pe[t * HDIM + 2 * i + 1] = cosf(a);
}

// ---------------- f32 -> bf16 convert ----------------
__global__ void cvt_kernel(const float* __restrict__ src, short* __restrict__ dst, int n) {
    int e0 = (blockIdx.x * 256 + threadIdx.x) * 4;
    if (e0 >= n) return;
    f32x4 v = *(const f32x4*)(src + e0);
    s16x4 o;
    for (int j = 0; j < 4; ++j) o[j] = f2bf(v[j]);
    *(s16x4*)(dst + e0) = o;
}

// ---------------- f32 [R][C] -> bf16 [C][R] transpose ----------------
__global__ __launch_bounds__(256)
void transpose_cvt_kernel(const float* __restrict__ src, short* __restrict__ dst,
                          int R, int C) {
    __shared__ short t[32][33];
    const int r0 = blockIdx.x * 32, c0 = blockIdx.y * 32;
    const int tr = threadIdx.x >> 3, tc4 = (threadIdx.x & 7) * 4;
    f32x4 v = *(const f32x4*)(src + (long)(r0 + tr) * C + c0 + tc4);
    for (int j = 0; j < 4; ++j) t[tc4 + j][tr] = f2bf(v[j]);
    __syncthreads();
    s16x4 o;
    for (int j = 0; j < 4; ++j) o[j] = t[tr][tc4 + j];
    *(s16x4*)(dst + (long)(c0 + tr) * R + r0 + tc4) = o;
}

// ---------------- bf16 MFMA GEMM: 128x128 tile, 4 waves (2x2), 4x4 frags/wave ----------------
// A [M][1024], Bt [N][1024] both row-major-in-K -> fully vectorized b128 staging.
template<int MODE>
__global__ __launch_bounds__(256)
void gemm_kernel(const short* __restrict__ A, const short* __restrict__ Bt,
                 const float* __restrict__ bq, const float* __restrict__ bkv,
                 const float* __restrict__ pe,
                 short* __restrict__ Qb, short* __restrict__ Kb, short* __restrict__ Vtb,
                 float* __restrict__ Cout) {
    const int tid = threadIdx.x, lane = tid & 63, wid = tid >> 6;
    const int l15 = lane & 15, lk = lane >> 4;
    const int m0 = blockIdx.x * 128, n0 = blockIdx.y * 128;
    const int wr = (wid >> 1) * 64, wc = (wid & 1) * 64;

    __shared__ short As[128 * 40];   // stride 40 shorts: 2-way-max bank aliasing (free)
    __shared__ short Bs[128 * 40];

    const int srow = tid >> 1, sc0 = (tid & 1) * 16;
    const short* Ag = A  + (long)(m0 + srow) * 1024 + sc0;
    const short* Bg = Bt + (long)(n0 + srow) * 1024 + sc0;

    f32x4 acc[4][4] = {};

    for (int k0 = 0; k0 < 1024; k0 += 32) {
        bf16x8 av0 = *(const bf16x8*)(Ag + k0);
        bf16x8 av1 = *(const bf16x8*)(Ag + k0 + 8);
        bf16x8 bv0 = *(const bf16x8*)(Bg + k0);
        bf16x8 bv1 = *(const bf16x8*)(Bg + k0 + 8);
        __syncthreads();                       // previous iter's reads complete
        *(bf16x8*)(As + srow * 40 + sc0)     = av0;
        *(bf16x8*)(As + srow * 40 + sc0 + 8) = av1;
        *(bf16x8*)(Bs + srow * 40 + sc0)     = bv0;
        *(bf16x8*)(Bs + srow * 40 + sc0 + 8) = bv1;
        __syncthreads();
        bf16x8 af[4], bf[4];
#pragma unroll
        for (int mi = 0; mi < 4; ++mi)
            af[mi] = *(const bf16x8*)(As + (wr + mi * 16 + l15) * 40 + lk * 8);
#pragma unroll
        for (int ni = 0; ni < 4; ++ni)
            bf[ni] = *(const bf16x8*)(Bs + (wc + ni * 16 + l15) * 40 + lk * 8);
#pragma unroll
        for (int mi = 0; mi < 4; ++mi)
#pragma unroll
            for (int ni = 0; ni < 4; ++ni)
                acc[mi][ni] = __builtin_amdgcn_mfma_f32_16x16x32_bf16(af[mi], bf[ni], acc[mi][ni], 0, 0, 0);
    }

    // epilogue; C/D layout: col = lane&15, row = (lane>>4)*4 + r
#pragma unroll
    for (int mi = 0; mi < 4; ++mi)
#pragma unroll
        for (int ni = 0; ni < 4; ++ni)
#pragma unroll
            for (int r = 0; r < 4; ++r) {
                int row = m0 + wr + mi * 16 + lk * 4 + r;
                int col = n0 + wc + ni * 16 + l15;
                float v = acc[mi][ni][r];
                if (MODE == 0) {
                    if (col < 1024) {            // Q: (+bq +pe) * QSCALE (base-2 softmax domain)
                        v = (v + bq[col] + pe[row * HDIM + (col & 127)]) * QSCALE;
                        Qb[(long)row * 1024 + col] = f2bf(v);
                    } else if (col < 1152) {     // K: +bkv[0:128] +pe
                        int d = col - 1024;
                        v += bkv[d] + pe[row * HDIM + d];
                        Kb[row * HDIM + d] = f2bf(v);
                    } else {                     // V: +bkv[128:256], store transposed [d][t]
                        v += bkv[col - 1024];
                        Vtb[(long)(col - 1152) * T_LEN + row] = f2bf(v);
                    }
                } else {
                    Cout[(long)row * 1024 + col] = v;
                }
            }
}

// ---------------- flash attention v4 ----------------
// 768 blocks: qt>=32 split into two key-range pieces (partials + combine), qt<32 full.
// Single-buffered K/V LDS (32KB) with T14 reg-prefetch across two barriers/tile.
// Swapped QK^T; lane-local softmax with defer-max; PV via K=16 MFMA (P in registers).
__global__ __launch_bounds__(256)
void attn_kernel(const short* __restrict__ Qb, const short* __restrict__ Kb,
                 const short* __restrict__ Vtb, short* __restrict__ Ob,
                 float* __restrict__ Opart, float* __restrict__ ml) {
    const int tid = threadIdx.x, lane = tid & 63, w = tid >> 6;
    const int l15 = lane & 15, lk = lane >> 4;
    int qt, h, s;    // s: 0 = low-half piece, 1 = high-half piece (diag), 2 = full (diag)
    const int bx = blockIdx.x;
    if (bx < 512) { qt = 63 - (bx >> 4); h = (bx >> 1) & 7; s = bx & 1; }
    else          { int j = bx - 512; qt = 31 - (j >> 3); h = j & 7; s = 2; }
    const int nkt = qt + 1, h0 = nkt >> 1;
    const int t0   = (s == 1) ? h0 : 0;
    const int tend = (s == 0) ? h0 : nkt;
    const bool diag = (s != 0);
    const int qw = qt * 64 + w * 16;

    __shared__ __align__(16) char Ks[64 * 256];     // K tile [key][d], XOR-swizzled
    __shared__ __align__(16) char Vts[128 * 128];   // V^T tile [d][key], XOR-swizzled

    // Q fragments (B-operand: col = l15 = query, k = lk*8+j). Pre-scaled by QSCALE.
    bf16x8 qa[4];
#pragma unroll
    for (int kc = 0; kc < 4; ++kc)
        qa[kc] = *(const bf16x8*)(Qb + (long)(qw + l15) * 1024 + h * HDIM + kc * 32 + lk * 8);

    f32x4 o[8] = {};
    f32x4 lsum4 = {};
    float m2 = -INFINITY;

    bf16x8 kreg[4], vreg[4];
#define LOADKV(kbase)                                                                     \
    _Pragma("unroll") for (int c = 0; c < 4; ++c) {                                       \
        int chunk = c * 256 + tid;                                                        \
        kreg[c] = *(const bf16x8*)(Kb + (long)((kbase) + (chunk >> 4)) * HDIM + (chunk & 15) * 8); \
        vreg[c] = *(const bf16x8*)(Vtb + (long)(chunk >> 3) * T_LEN + (kbase) + (chunk & 7) * 8);  \
    }
#define WRITEKV()                                                                         \
    _Pragma("unroll") for (int c = 0; c < 4; ++c) {                                       \
        int chunk = c * 256 + tid;                                                        \
        int krow = chunk >> 4, kc8 = (chunk & 15) * 8;                                    \
        *(bf16x8*)(Ks + ((krow * 256 + kc8 * 2) ^ ((krow & 7) << 4))) = kreg[c];          \
        int vd = chunk >> 3, vk8 = (chunk & 7) * 8;                                       \
        *(bf16x8*)(Vts + ((vd * 128 + vk8 * 2) ^ ((vd & 7) << 4))) = vreg[c];             \
    }

    LOADKV(t0 * 64);
    WRITEKV();
    __syncthreads();

    for (int t = t0; t < tend; ++t) {
        const bool pf = (t + 1 < tend);
        if (pf) { LOADKV((t + 1) * 64); }   // T14: issue early, write after barrier

        // S^T = K @ Q^T : lane holds S[key ct*16+lk*4+r][query l15]
        f32x4 S[4];
        __builtin_amdgcn_s_setprio(1);
#pragma unroll
        for (int ct = 0; ct < 4; ++ct) {
            f32x4 sacc = {};
#pragma unroll
            for (int kc = 0; kc < 4; ++kc) {
                int row = ct * 16 + l15;
                bf16x8 a = *(const bf16x8*)(Ks + ((row * 256 + kc * 64 + lk * 16) ^ ((row & 7) << 4)));
                sacc = __builtin_amdgcn_mfma_f32_16x16x32_bf16(a, qa[kc], sacc, 0, 0, 0);
            }
            S[ct] = sacc;
        }
        __builtin_amdgcn_s_setprio(0);

        if (diag && t == tend - 1) {    // causal mask: only the diagonal tile
            const int query = qw + l15, kb = t * 64;
#pragma unroll
            for (int ct = 0; ct < 4; ++ct)
#pragma unroll
                for (int r = 0; r < 4; ++r)
                    if (kb + ct * 16 + lk * 4 + r > query) S[ct][r] = -1e30f;
        }

        // defer-max online softmax (base-2), all state lane-local for query l15
        float pmax = S[0][0];
#pragma unroll
        for (int ct = 0; ct < 4; ++ct)
#pragma unroll
            for (int j = 0; j < 4; ++j)
                pmax = fmaxf(pmax, S[ct][j]);
        if (!__all(pmax <= m2 + 8.f)) {     // slow path: real max update + rescale
            float tm = pmax;
            tm = fmaxf(tm, __shfl_xor(tm, 16));
            tm = fmaxf(tm, __shfl_xor(tm, 32));
            float nm = fmaxf(m2, tm);
            float sc = __builtin_amdgcn_exp2f(m2 - nm);
            m2 = nm;
            lsum4 *= sc;
            f32x4 scq;
#pragma unroll
            for (int r = 0; r < 4; ++r) scq[r] = __shfl(sc, lk * 4 + r);
#pragma unroll
            for (int dt = 0; dt < 8; ++dt) o[dt] *= scq;
        }
        s16x4 pa[4];
#pragma unroll
        for (int ct = 0; ct < 4; ++ct) {
#pragma unroll
            for (int j = 0; j < 4; ++j)
                S[ct][j] = __builtin_amdgcn_exp2f(S[ct][j] - m2);
            lsum4 += S[ct];
            u32x2 pk = {cvt_pk_bf16(S[ct][0], S[ct][1]), cvt_pk_bf16(S[ct][2], S[ct][3])};
            pa[ct] = __builtin_bit_cast(s16x4, pk);
        }

        // O += P @ V  (A = P in registers, B = V^T b64 fragments from LDS)
        __builtin_amdgcn_s_setprio(1);
#pragma unroll
        for (int dt = 0; dt < 8; ++dt) {
            int vrow = dt * 16 + l15;
#pragma unroll
            for (int ct = 0; ct < 4; ++ct) {
                s16x4 vb = *(const s16x4*)(Vts + ((vrow * 128 + ct * 32 + lk * 8) ^ ((vrow & 7) << 4)));
                o[dt] = mfma16(pa[ct], vb, o[dt]);
            }
        }
        __builtin_amdgcn_s_setprio(0);

        __syncthreads();                 // all waves done reading Ks/Vts for tile t
        if (pf) { WRITEKV(); }
        __syncthreads();                 // writes visible before next tile's reads
    }

    // epilogue
    float lsum = (lsum4[0] + lsum4[1]) + (lsum4[2] + lsum4[3]);
    lsum += __shfl_xor(lsum, 16);
    lsum += __shfl_xor(lsum, 32);

    if (s == 2) {
        f32x4 rl;
#pragma unroll
        for (int r = 0; r < 4; ++r) rl[r] = 1.0f / __shfl(lsum, lk * 4 + r);
#pragma unroll
        for (int dt = 0; dt < 8; ++dt)
#pragma unroll
            for (int r = 0; r < 4; ++r) {
                int row = qw + lk * 4 + r;
                Ob[(long)row * 1024 + h * HDIM + dt * 16 + l15] = f2bf(o[dt][r] * rl[r]);
            }
    } else {
        const int pidx = (qt - 32) * 8 + h;
        float* Op = Opart + (long)(pidx * 2 + s) * 64 * 128;
#pragma unroll
        for (int dt = 0; dt < 8; ++dt)
#pragma unroll
            for (int r = 0; r < 4; ++r)
                Op[(w * 16 + lk * 4 + r) * 128 + dt * 16 + l15] = o[dt][r];
        if (lk == 0) {
            float* mlp = ml + ((pidx * 2 + s) * 64 + w * 16 + l15) * 2;
            mlp[0] = m2; mlp[1] = lsum;
        }
    }
#undef LOADKV
#undef WRITEKV
}

// ---------------- combine two key-range partials (qt >= 32) ----------------
__global__ __launch_bounds__(256)
void combine_kernel(const float* __restrict__ Opart, const float* __restrict__ ml,
                    short* __restrict__ Ob) {
    const int pidx = blockIdx.x;                 // 0..255
    const int qt = 32 + (pidx >> 3), h = pidx & 7;
    const int q = threadIdx.x >> 2, d0 = (threadIdx.x & 3) * 32;
    const float* ml1 = ml + ((pidx * 2 + 0) * 64 + q) * 2;
    const float* ml2 = ml + ((pidx * 2 + 1) * 64 + q) * 2;
    float m1 = ml1[0], l1 = ml1[1], mB = ml2[0], l2 = ml2[1];
    float m = fmaxf(m1, mB);
    float c1 = __builtin_amdgcn_exp2f(m1 - m), c2 = __builtin_amdgcn_exp2f(mB - m);
    float inv = 1.0f / (l1 * c1 + l2 * c2);
    const float* O1 = Opart + (long)(pidx * 2 + 0) * 8192 + q * 128 + d0;
    const float* O2 = Opart + (long)(pidx * 2 + 1) * 8192 + q * 128 + d0;
    short* dst = Ob + (long)(qt * 64 + q) * 1024 + h * HDIM + d0;
#pragma unroll
    for (int dd = 0; dd < 32; dd += 4) {
        f32x4 a = *(const f32x4*)(O1 + dd);
        f32x4 b = *(const f32x4*)(O2 + dd);
        s16x4 r;
#pragma unroll
        for (int j = 0; j < 4; ++j) r[j] = f2bf((a[j] * c1 + b[j] * c2) * inv);
        *(s16x4*)(dst + dd) = r;
    }
}

extern "C" void kernel_launch(void* const* d_in, const int* in_sizes, int n_in,
                              void* d_out, int out_size, void* d_ws, size_t ws_size,
                              hipStream_t stream) {
    const float* x   = (const float*)d_in[0];
    const float* Wq  = (const float*)d_in[1];
    const float* bq  = (const float*)d_in[2];
    const float* Wkv = (const float*)d_in[3];
    const float* bkv = (const float*)d_in[4];
    const float* Wo  = (const float*)d_in[5];
    float* out = (float*)d_out;
    char* ws = (char*)d_ws;

    float* pe    = (float*)(ws);                      // 2 MiB
    short* xb    = (short*)(ws + (2l  << 20));        // 8 MiB
    short* wt    = (short*)(ws + (10l << 20));        // 2.5 MiB  (W^T: [n][k], Q|K|V rows)
    short* wot   = (short*)(ws + (13l << 20));        // 2 MiB    (Wo^T)
    short* Qb    = (short*)(ws + (15l << 20));        // 8 MiB
    short* Kb    = (short*)(ws + (23l << 20));        // 1 MiB
    short* Vtb   = (short*)(ws + (24l << 20));        // 1 MiB
    short* Ab    = (short*)(ws + (25l << 20));        // 8 MiB
    float* Opart = (float*)(ws + (33l << 20));        // 16 MiB   (split partials)
    float* ml    = (float*)(ws + (49l << 20));        // 0.5 MiB  (m,l per split row)

    pe_kernel<<<1024, 256, 0, stream>>>(pe);
    cvt_kernel<<<4096, 256, 0, stream>>>(x, xb, T_LEN * EMB);
    transpose_cvt_kernel<<<dim3(32, 32), 256, 0, stream>>>(Wq,  wt,               EMB, 1024);
    transpose_cvt_kernel<<<dim3(32, 8),  256, 0, stream>>>(Wkv, wt + 1024 * 1024, EMB, 256);
    transpose_cvt_kernel<<<dim3(32, 32), 256, 0, stream>>>(Wo,  wot,              EMB, 1024);

    gemm_kernel<0><<<dim3(32, 10), 256, 0, stream>>>(xb, wt, bq, bkv, pe,
                                                     Qb, Kb, Vtb, nullptr);
    attn_kernel<<<768, 256, 0, stream>>>(Qb, Kb, Vtb, Ab, Opart, ml);
    combine_kernel<<<256, 256, 0, stream>>>(Opart, ml, Ab);
    gemm_kernel<1><<<dim3(32, 8), 256, 0, stream>>>(Ab, wot, nullptr, nullptr, nullptr,
                                                    nullptr, nullptr, nullptr, out);
}

// Round 6
// 172.678 us; speedup vs baseline: 2.8542x; 1.0813x over previous
//
#include <hip/hip_runtime.h>
#include <hip/hip_bf16.h>

#define T_LEN 4096
#define EMB   1024
#define HDIM  128
#define QSCALE 0.12752039955379307f   // (1/sqrt(128)) * log2(e) -- folded into Q

typedef __attribute__((ext_vector_type(8))) short bf16x8;
typedef __attribute__((ext_vector_type(4))) short s16x4;
typedef __attribute__((ext_vector_type(4))) float f32x4;
typedef __attribute__((ext_vector_type(16))) float f32x16;
typedef __attribute__((ext_vector_type(4))) unsigned u32x4;

__device__ __forceinline__ short f2bf(float f) {
    unsigned u = __builtin_bit_cast(unsigned, f);
    u += 0x7fffu + ((u >> 16) & 1u);   // RNE
    return (short)(u >> 16);
}

__device__ __forceinline__ unsigned cvt_pk_bf16(float lo, float hi) {
    unsigned r;
    asm("v_cvt_pk_bf16_f32 %0, %1, %2" : "=v"(r) : "v"(lo), "v"(hi));
    return r;
}

// exchange a.hi32lanes <-> b.lo32lanes (T12)
__device__ __forceinline__ void plswap(unsigned &a, unsigned &b) {
#if __has_builtin(__builtin_amdgcn_permlane32_swap)
    auto r = __builtin_amdgcn_permlane32_swap(a, b, false, false);
    a = r[0]; b = r[1];
#else
    asm volatile("v_permlane32_swap_b32 %0, %1" : "+v"(a), "+v"(b));
#endif
}

__device__ __forceinline__ bf16x8 mk8(unsigned a, unsigned b, unsigned c, unsigned d) {
    u32x4 v = {a, b, c, d};
    return __builtin_bit_cast(bf16x8, v);
}

// async global->LDS DMA, 16B/lane; lds ptr must be the wave-uniform base (HW adds lane*16)
__device__ __forceinline__ void gload16(const short* g, const char* l) {
    __builtin_amdgcn_global_load_lds(
        (const __attribute__((address_space(1))) unsigned*)g,
        (__attribute__((address_space(3))) unsigned*)l, 16, 0, 0);
}

// ---------------- PE table ----------------
__global__ void pe_kernel(float* __restrict__ pe) {
    int idx = blockIdx.x * 256 + threadIdx.x;
    if (idx >= T_LEN * 64) return;
    int t = idx >> 6, i = idx & 63;
    float f = expf(-9.210340371976184f * (float)i / 64.0f);
    float a = (float)t * f;
    pe[t * HDIM + 2 * i]     = sinf(a);
    pe[t * HDIM + 2 * i + 1] = cosf(a);
}

// ---------------- f32 -> bf16 convert ----------------
__global__ void cvt_kernel(const float* __restrict__ src, short* __restrict__ dst, int n) {
    int e0 = (blockIdx.x * 256 + threadIdx.x) * 4;
    if (e0 >= n) return;
    f32x4 v = *(const f32x4*)(src + e0);
    s16x4 o;
    for (int j = 0; j < 4; ++j) o[j] = f2bf(v[j]);
    *(s16x4*)(dst + e0) = o;
}

// ---------------- f32 [R][C] -> bf16 [C][R] transpose ----------------
__global__ __launch_bounds__(256)
void transpose_cvt_kernel(const float* __restrict__ src, short* __restrict__ dst,
                          int R, int C) {
    __shared__ short t[32][33];
    const int r0 = blockIdx.x * 32, c0 = blockIdx.y * 32;
    const int tr = threadIdx.x >> 3, tc4 = (threadIdx.x & 7) * 4;
    f32x4 v = *(const f32x4*)(src + (long)(r0 + tr) * C + c0 + tc4);
    for (int j = 0; j < 4; ++j) t[tc4 + j][tr] = f2bf(v[j]);
    __syncthreads();
    s16x4 o;
    for (int j = 0; j < 4; ++j) o[j] = t[tr][tc4 + j];
    *(s16x4*)(dst + (long)(c0 + tr) * R + r0 + tc4) = o;
}

// ---------------- bf16 MFMA GEMM: 128x128 tile, 4 waves (2x2), 4x4 frags/wave ----------------
template<int MODE>
__global__ __launch_bounds__(256)
void gemm_kernel(const short* __restrict__ A, const short* __restrict__ Bt,
                 const float* __restrict__ bq, const float* __restrict__ bkv,
                 const float* __restrict__ pe,
                 short* __restrict__ Qb, short* __restrict__ Kb, short* __restrict__ Vtb,
                 float* __restrict__ Cout) {
    const int tid = threadIdx.x, lane = tid & 63, wid = tid >> 6;
    const int l15 = lane & 15, lk = lane >> 4;
    const int m0 = blockIdx.x * 128, n0 = blockIdx.y * 128;
    const int wr = (wid >> 1) * 64, wc = (wid & 1) * 64;

    __shared__ short As[128 * 40];
    __shared__ short Bs[128 * 40];

    const int srow = tid >> 1, sc0 = (tid & 1) * 16;
    const short* Ag = A  + (long)(m0 + srow) * 1024 + sc0;
    const short* Bg = Bt + (long)(n0 + srow) * 1024 + sc0;

    f32x4 acc[4][4] = {};

    for (int k0 = 0; k0 < 1024; k0 += 32) {
        bf16x8 av0 = *(const bf16x8*)(Ag + k0);
        bf16x8 av1 = *(const bf16x8*)(Ag + k0 + 8);
        bf16x8 bv0 = *(const bf16x8*)(Bg + k0);
        bf16x8 bv1 = *(const bf16x8*)(Bg + k0 + 8);
        __syncthreads();
        *(bf16x8*)(As + srow * 40 + sc0)     = av0;
        *(bf16x8*)(As + srow * 40 + sc0 + 8) = av1;
        *(bf16x8*)(Bs + srow * 40 + sc0)     = bv0;
        *(bf16x8*)(Bs + srow * 40 + sc0 + 8) = bv1;
        __syncthreads();
        bf16x8 af[4], bf[4];
#pragma unroll
        for (int mi = 0; mi < 4; ++mi)
            af[mi] = *(const bf16x8*)(As + (wr + mi * 16 + l15) * 40 + lk * 8);
#pragma unroll
        for (int ni = 0; ni < 4; ++ni)
            bf[ni] = *(const bf16x8*)(Bs + (wc + ni * 16 + l15) * 40 + lk * 8);
#pragma unroll
        for (int mi = 0; mi < 4; ++mi)
#pragma unroll
            for (int ni = 0; ni < 4; ++ni)
                acc[mi][ni] = __builtin_amdgcn_mfma_f32_16x16x32_bf16(af[mi], bf[ni], acc[mi][ni], 0, 0, 0);
    }

#pragma unroll
    for (int mi = 0; mi < 4; ++mi)
#pragma unroll
        for (int ni = 0; ni < 4; ++ni)
#pragma unroll
            for (int r = 0; r < 4; ++r) {
                int row = m0 + wr + mi * 16 + lk * 4 + r;
                int col = n0 + wc + ni * 16 + l15;
                float v = acc[mi][ni][r];
                if (MODE == 0) {
                    if (col < 1024) {            // Q: (+bq +pe) * QSCALE (base-2 domain)
                        v = (v + bq[col] + pe[row * HDIM + (col & 127)]) * QSCALE;
                        Qb[(long)row * 1024 + col] = f2bf(v);
                    } else if (col < 1152) {     // K: +bkv[0:128] +pe
                        int d = col - 1024;
                        v += bkv[d] + pe[row * HDIM + d];
                        Kb[row * HDIM + d] = f2bf(v);
                    } else {                     // V: +bkv[128:256], transposed [d][t]
                        v += bkv[col - 1024];
                        Vtb[(long)(col - 1152) * T_LEN + row] = f2bf(v);
                    }
                } else {
                    Cout[(long)row * 1024 + col] = v;
                }
            }
}

// ---------------- flash attention v5: 32x32 MFMA, DMA-staged K/V, P in registers ----------------
// 384 blocks: 128-query q-blocks; j>=16 split into two key-range pieces (partials+combine).
// K/V double-buffered via global_load_lds (linear LDS dest, inverse-swizzled global src),
// one barrier/tile. Swapped QK^T (q = lane&31), softmax lane-local + 1 shfl_xor(32);
// P->PV A-frags via cvt_pk + permlane32_swap. Defer-max (T13).
__global__ __launch_bounds__(256, 2)
void attn_kernel(const short* __restrict__ Qb, const short* __restrict__ Kb,
                 const short* __restrict__ Vtb, short* __restrict__ Ob,
                 float* __restrict__ Opart, float* __restrict__ ml) {
    const int tid = threadIdx.x, lane = tid & 63, w = tid >> 6;
    const int q31 = lane & 31, hi = lane >> 5;

    int j, h, s;    // s: 0 = low-half keys, 1 = high-half (diag), 2 = full (diag)
    const int bx = blockIdx.x;
    if (bx < 256) { j = 31 - (bx >> 4); h = (bx >> 1) & 7; s = bx & 1; }
    else          { int p = bx - 256; j = 15 - (p >> 3); h = p & 7; s = 2; }
    const int nkt = 2 * j + 2;
    const int t0   = (s == 1) ? (j + 1) : 0;
    const int tend = (s == 0) ? (j + 1) : nkt;
    const int mask_from = (s == 0) ? 0x7fffffff : 2 * j;   // only last 2 tiles need masking
    const int qw = j * 128 + w * 32;

    __shared__ __align__(16) char Ks[2][64 * 256];     // K [key][d] bf16, chunk-swizzled
    __shared__ __align__(16) char Vts[2][128 * 128];   // V^T [d][key] bf16, chunk-swizzled

    // Q B-frags: col = q31 = query, k = kc*16 + hi*8 + jj. Pre-scaled by QSCALE.
    bf16x8 qf[8];
#pragma unroll
    for (int kc = 0; kc < 8; ++kc)
        qf[kc] = *(const bf16x8*)(Qb + (long)(qw + q31) * 1024 + h * HDIM + kc * 16 + hi * 8);

    f32x16 o[4] = {};
    float m2 = -INFINITY, lsum = 0.f;
    const int swz = (q31 & 7) << 4;

    // DMA stage: LDS linear (wave-uniform base, HW adds lane*16); swizzle applied to the
    // per-lane GLOBAL chunk (involution c ^= row&7) so reads can use byte^((row&7)<<4).
#define STAGE(buf, kbase) do {                                                          \
    _Pragma("unroll") for (int i_ = 0; i_ < 4; ++i_) {                                  \
        int id_ = (w * 4 + i_) * 64 + lane;                                             \
        int ky_ = id_ >> 4, kc_ = id_ & 15;                                             \
        gload16(Kb + (long)((kbase) + ky_) * HDIM + ((kc_ ^ (ky_ & 7)) * 8),            \
                Ks[buf] + (w * 4 + i_) * 1024);                                         \
        int d_ = id_ >> 3, vc_ = id_ & 7;                                               \
        gload16(Vtb + (long)d_ * T_LEN + (kbase) + ((vc_ ^ (d_ & 7)) * 8),              \
                Vts[buf] + (w * 4 + i_) * 1024);                                        \
    } } while (0)

    STAGE(0, t0 * 64);

    for (int t = t0; t < tend; ++t) {
        const int cur = (t - t0) & 1;
        __syncthreads();                       // compiler drains vmcnt(0): tile t landed
        if (t + 1 < tend) STAGE(cur ^ 1, (t + 1) * 64);

        // S^T = K @ Q^T : D[key][q], col = q31 = query, row = crow(r,hi) = (r&3)+8*(r>>2)+4*hi
        const char* Kbuf = Ks[cur];
        f32x16 S0 = {}, S1 = {};
        __builtin_amdgcn_s_setprio(1);
#pragma unroll
        for (int kc = 0; kc < 8; ++kc) {
            bf16x8 a0 = *(const bf16x8*)(Kbuf + q31 * 256 + ((kc * 32 + hi * 16) ^ swz));
            bf16x8 a1 = *(const bf16x8*)(Kbuf + (32 + q31) * 256 + ((kc * 32 + hi * 16) ^ swz));
            S0 = __builtin_amdgcn_mfma_f32_32x32x16_bf16(a0, qf[kc], S0, 0, 0, 0);
            S1 = __builtin_amdgcn_mfma_f32_32x32x16_bf16(a1, qf[kc], S1, 0, 0, 0);
        }
        __builtin_amdgcn_s_setprio(0);

        if (t >= mask_from) {
            const int query = qw + q31, kb = t * 64 + 4 * hi;
#pragma unroll
            for (int r = 0; r < 16; ++r) {
                int krow = kb + (r & 3) + 8 * (r >> 2);
                if (krow > query)      S0[r] = -1e30f;
                if (krow + 32 > query) S1[r] = -1e30f;
            }
        }

        // defer-max online softmax (base-2); lane owns query q31 (both hi halves, split keys)
        float pmax = fmaxf(S0[0], S1[0]);
#pragma unroll
        for (int r = 1; r < 16; ++r) pmax = fmaxf(pmax, fmaxf(S0[r], S1[r]));
        if (!__all(pmax <= m2 + 8.f)) {        // slow path: real max update + O rescale
            float tm = fmaxf(pmax, __shfl_xor(pmax, 32));
            float nm = fmaxf(m2, tm);
            float sc = __builtin_amdgcn_exp2f(m2 - nm);
            m2 = nm;
            lsum *= sc;
#pragma unroll
            for (int r = 0; r < 16; ++r) {     // O rows are queries crow(r,hi)
                float scr = __shfl(sc, (r & 3) + 8 * (r >> 2) + 4 * hi);
                o[0][r] *= scr; o[1][r] *= scr; o[2][r] *= scr; o[3][r] *= scr;
            }
        }

        // exp2 + pack P; key pairs per word: w[i] holds keys (2i..)+4*hi per crow mapping
        unsigned pw0[8], pw1[8];
#pragma unroll
        for (int i = 0; i < 8; ++i) {
            float e0 = __builtin_amdgcn_exp2f(S0[2 * i] - m2);
            float e1 = __builtin_amdgcn_exp2f(S0[2 * i + 1] - m2);
            float f0 = __builtin_amdgcn_exp2f(S1[2 * i] - m2);
            float f1 = __builtin_amdgcn_exp2f(S1[2 * i + 1] - m2);
            lsum += (e0 + e1) + (f0 + f1);
            pw0[i] = cvt_pk_bf16(e0, e1);
            pw1[i] = cvt_pk_bf16(f0, f1);
        }
        // redistribute to PV A-frag layout: lane(q,hi) needs keys 16ks + 8hi .. +8
        plswap(pw0[0], pw0[2]); plswap(pw0[1], pw0[3]);
        plswap(pw0[4], pw0[6]); plswap(pw0[5], pw0[7]);
        plswap(pw1[0], pw1[2]); plswap(pw1[1], pw1[3]);
        plswap(pw1[4], pw1[6]); plswap(pw1[5], pw1[7]);
        bf16x8 pfr[4];
        pfr[0] = mk8(pw0[0], pw0[1], pw0[2], pw0[3]);
        pfr[1] = mk8(pw0[4], pw0[5], pw0[6], pw0[7]);
        pfr[2] = mk8(pw1[0], pw1[1], pw1[2], pw1[3]);
        pfr[3] = mk8(pw1[4], pw1[5], pw1[6], pw1[7]);

        // O += P @ V : A = P (rows=q), B = V^T (col = q31 = d_local, k = keys)
        const char* Vbuf = Vts[cur];
        __builtin_amdgcn_s_setprio(1);
#pragma unroll
        for (int ks = 0; ks < 4; ++ks)
#pragma unroll
            for (int dt = 0; dt < 4; ++dt) {
                bf16x8 vb = *(const bf16x8*)(Vbuf + (dt * 32 + q31) * 128 + ((ks * 32 + hi * 16) ^ swz));
                o[dt] = __builtin_amdgcn_mfma_f32_32x32x16_bf16(pfr[ks], vb, o[dt], 0, 0, 0);
            }
        __builtin_amdgcn_s_setprio(0);
    }
#undef STAGE

    lsum += __shfl_xor(lsum, 32);              // merge the two key-halves

    if (s == 2) {
        float inv = 1.f / lsum;
#pragma unroll
        for (int r = 0; r < 16; ++r) {
            int qrow = (r & 3) + 8 * (r >> 2) + 4 * hi;
            float rl = __shfl(inv, qrow);
            short* dst = Ob + (long)(qw + qrow) * 1024 + h * HDIM + q31;
            dst[0]  = f2bf(o[0][r] * rl);
            dst[32] = f2bf(o[1][r] * rl);
            dst[64] = f2bf(o[2][r] * rl);
            dst[96] = f2bf(o[3][r] * rl);
        }
    } else {
        const int pidx = ((j - 16) * 8 + h) * 2 + s;
        float* Op = Opart + (long)pidx * (128 * 128);
#pragma unroll
        for (int r = 0; r < 16; ++r) {
            int qrow = (r & 3) + 8 * (r >> 2) + 4 * hi;
            float* dst = Op + (w * 32 + qrow) * 128 + q31;
            dst[0] = o[0][r]; dst[32] = o[1][r]; dst[64] = o[2][r]; dst[96] = o[3][r];
        }
        if (hi == 0) {
            float* mlp = ml + ((long)pidx * 128 + w * 32 + q31) * 2;
            mlp[0] = m2; mlp[1] = lsum;
        }
    }
}

// ---------------- combine two key-range partials (j >= 16) ----------------
__global__ __launch_bounds__(256)
void combine_kernel(const float* __restrict__ Opart, const float* __restrict__ ml,
                    short* __restrict__ Ob) {
    const int pp = blockIdx.x;                 // 0..127
    const int j = 16 + (pp >> 3), h = pp & 7;
    const int q = threadIdx.x >> 1, dh = (threadIdx.x & 1) * 64;
    const float* mlA = ml + ((long)(pp * 2 + 0) * 128 + q) * 2;
    const float* mlB = ml + ((long)(pp * 2 + 1) * 128 + q) * 2;
    float m1 = mlA[0], l1 = mlA[1], mB = mlB[0], l2 = mlB[1];
    float m = fmaxf(m1, mB);
    float c1 = __builtin_amdgcn_exp2f(m1 - m), c2 = __builtin_amdgcn_exp2f(mB - m);
    float inv = 1.0f / (l1 * c1 + l2 * c2);
    const float* O1 = Opart + (long)(pp * 2 + 0) * 16384 + q * 128 + dh;
    const float* O2 = Opart + (long)(pp * 2 + 1) * 16384 + q * 128 + dh;
    short* dst = Ob + (long)(j * 128 + q) * 1024 + h * HDIM + dh;
#pragma unroll
    for (int dd = 0; dd < 64; dd += 4) {
        f32x4 a = *(const f32x4*)(O1 + dd);
        f32x4 b = *(const f32x4*)(O2 + dd);
        s16x4 r;
#pragma unroll
        for (int jj = 0; jj < 4; ++jj) r[jj] = f2bf((a[jj] * c1 + b[jj] * c2) * inv);
        *(s16x4*)(dst + dd) = r;
    }
}

extern "C" void kernel_launch(void* const* d_in, const int* in_sizes, int n_in,
                              void* d_out, int out_size, void* d_ws, size_t ws_size,
                              hipStream_t stream) {
    const float* x   = (const float*)d_in[0];
    const float* Wq  = (const float*)d_in[1];
    const float* bq  = (const float*)d_in[2];
    const float* Wkv = (const float*)d_in[3];
    const float* bkv = (const float*)d_in[4];
    const float* Wo  = (const float*)d_in[5];
    float* out = (float*)d_out;
    char* ws = (char*)d_ws;

    float* pe    = (float*)(ws);                      // 2 MiB
    short* xb    = (short*)(ws + (2l  << 20));        // 8 MiB
    short* wt    = (short*)(ws + (10l << 20));        // 2.5 MiB  (W^T: [n][k])
    short* wot   = (short*)(ws + (13l << 20));        // 2 MiB    (Wo^T)
    short* Qb    = (short*)(ws + (15l << 20));        // 8 MiB
    short* Kb    = (short*)(ws + (23l << 20));        // 1 MiB
    short* Vtb   = (short*)(ws + (24l << 20));        // 1 MiB
    short* Ab    = (short*)(ws + (25l << 20));        // 8 MiB
    float* Opart = (float*)(ws + (33l << 20));        // 16 MiB   (split partials)
    float* ml    = (float*)(ws + (49l << 20));        // 256 KiB  (m,l per split row)

    pe_kernel<<<1024, 256, 0, stream>>>(pe);
    cvt_kernel<<<4096, 256, 0, stream>>>(x, xb, T_LEN * EMB);
    transpose_cvt_kernel<<<dim3(32, 32), 256, 0, stream>>>(Wq,  wt,               EMB, 1024);
    transpose_cvt_kernel<<<dim3(32, 8),  256, 0, stream>>>(Wkv, wt + 1024 * 1024, EMB, 256);
    transpose_cvt_kernel<<<dim3(32, 32), 256, 0, stream>>>(Wo,  wot,              EMB, 1024);

    gemm_kernel<0><<<dim3(32, 10), 256, 0, stream>>>(xb, wt, bq, bkv, pe,
                                                     Qb, Kb, Vtb, nullptr);
    attn_kernel<<<384, 256, 0, stream>>>(Qb, Kb, Vtb, Ab, Opart, ml);
    combine_kernel<<<128, 256, 0, stream>>>(Opart, ml, Ab);
    gemm_kernel<1><<<dim3(32, 8), 256, 0, stream>>>(Ab, wot, nullptr, nullptr, nullptr,
                                                    nullptr, nullptr, nullptr, out);
}

// Round 7
// 158.576 us; speedup vs baseline: 3.1080x; 1.0889x over previous
//
#include <hip/hip_runtime.h>
#include <hip/hip_bf16.h>

#define T_LEN 4096
#define EMB   1024
#define HDIM  128
#define QSCALE 0.12752039955379307f   // (1/sqrt(128)) * log2(e) -- folded into Q

typedef __attribute__((ext_vector_type(8))) short bf16x8;
typedef __attribute__((ext_vector_type(4))) short s16x4;
typedef __attribute__((ext_vector_type(4))) float f32x4;
typedef __attribute__((ext_vector_type(16))) float f32x16;
typedef __attribute__((ext_vector_type(4))) unsigned u32x4;

__device__ __forceinline__ short f2bf(float f) {
    unsigned u = __builtin_bit_cast(unsigned, f);
    u += 0x7fffu + ((u >> 16) & 1u);   // RNE
    return (short)(u >> 16);
}
__device__ __forceinline__ float bf2f(short s) {
    unsigned u = ((unsigned)(unsigned short)s) << 16;
    return __builtin_bit_cast(float, u);
}

__device__ __forceinline__ unsigned cvt_pk_bf16(float lo, float hi) {
    unsigned r;
    asm("v_cvt_pk_bf16_f32 %0, %1, %2" : "=v"(r) : "v"(lo), "v"(hi));
    return r;
}

// exchange a.hi32lanes <-> b.lo32lanes (T12)
__device__ __forceinline__ void plswap(unsigned &a, unsigned &b) {
#if __has_builtin(__builtin_amdgcn_permlane32_swap)
    auto r = __builtin_amdgcn_permlane32_swap(a, b, false, false);
    a = r[0]; b = r[1];
#else
    asm volatile("v_permlane32_swap_b32 %0, %1" : "+v"(a), "+v"(b));
#endif
}

__device__ __forceinline__ bf16x8 mk8(unsigned a, unsigned b, unsigned c, unsigned d) {
    u32x4 v = {a, b, c, d};
    return __builtin_bit_cast(bf16x8, v);
}

// async global->LDS DMA, 16B/lane; lds ptr = wave-uniform base (HW adds lane*16)
__device__ __forceinline__ void gload16(const short* g, const char* l) {
    __builtin_amdgcn_global_load_lds(
        (const __attribute__((address_space(1))) unsigned*)g,
        (__attribute__((address_space(3))) unsigned*)l, 16, 0, 0);
}

// ---------------- PE table ----------------
__global__ void pe_kernel(float* __restrict__ pe) {
    int idx = blockIdx.x * 256 + threadIdx.x;
    if (idx >= T_LEN * 64) return;
    int t = idx >> 6, i = idx & 63;
    float f = expf(-9.210340371976184f * (float)i / 64.0f);
    float a = (float)t * f;
    pe[t * HDIM + 2 * i]     = sinf(a);
    pe[t * HDIM + 2 * i + 1] = cosf(a);
}

// ---------------- f32 -> bf16 convert ----------------
__global__ void cvt_kernel(const float* __restrict__ src, short* __restrict__ dst, int n) {
    int e0 = (blockIdx.x * 256 + threadIdx.x) * 4;
    if (e0 >= n) return;
    f32x4 v = *(const f32x4*)(src + e0);
    s16x4 o;
    for (int j = 0; j < 4; ++j) o[j] = f2bf(v[j]);
    *(s16x4*)(dst + e0) = o;
}

// ---------------- f32 [R][C] -> bf16 [C][R] transpose ----------------
__global__ __launch_bounds__(256)
void transpose_cvt_kernel(const float* __restrict__ src, short* __restrict__ dst,
                          int R, int C) {
    __shared__ short t[32][33];
    const int r0 = blockIdx.x * 32, c0 = blockIdx.y * 32;
    const int tr = threadIdx.x >> 3, tc4 = (threadIdx.x & 7) * 4;
    f32x4 v = *(const f32x4*)(src + (long)(r0 + tr) * C + c0 + tc4);
    for (int j = 0; j < 4; ++j) t[tc4 + j][tr] = f2bf(v[j]);
    __syncthreads();
    s16x4 o;
    for (int j = 0; j < 4; ++j) o[j] = t[tr][tc4 + j];
    *(s16x4*)(dst + (long)(c0 + tr) * R + r0 + tc4) = o;
}

// ---------------- bf16 MFMA GEMM, m97 structure: 128x128 tile, BK=32, dbuf gload_lds ----------------
// A [M][1024], Bt [N][1024]; LDS [128][32] linear; source pre-swizzled (col^=row&3) so
// frag reads at byte row*64 + ((lk^(row&3))*16) are conflict-free. One barrier/K-step.
template<int MODE>
__global__ __launch_bounds__(256)
void gemm_kernel(const short* __restrict__ A, const short* __restrict__ Bt,
                 const float* __restrict__ bq, const float* __restrict__ bkv,
                 const float* __restrict__ pe,
                 short* __restrict__ Qb, short* __restrict__ Kb, short* __restrict__ Vtb,
                 float* __restrict__ Cout) {
    const int tid = threadIdx.x, lane = tid & 63, wid = tid >> 6;
    const int l15 = lane & 15, lk = lane >> 4;
    const int m0 = blockIdx.x * 128, n0 = blockIdx.y * 128;
    const int wr = (wid >> 1) * 64, wc = (wid & 1) * 64;

    __shared__ __align__(16) short As[2][128 * 32];
    __shared__ __align__(16) short Bs[2][128 * 32];

    // wave stages chunks {2w, 2w+1} of A and B (chunk = 16 rows = 1KB)
    const int srowA = 2 * wid * 16 + (lane >> 2);
    const int scol  = ((lane & 3) ^ ((lane >> 2) & 3)) * 8;   // inverse-swizzled source col

#define GSTAGE(buf, k0) do {                                                            \
    _Pragma("unroll") for (int i_ = 0; i_ < 2; ++i_) {                                  \
        int row_ = srowA + i_ * 16;                                                     \
        gload16(A  + (long)(m0 + row_) * 1024 + (k0) + scol,                            \
                (const char*)(As[buf] + (2 * wid + i_) * 512));                         \
        gload16(Bt + (long)(n0 + row_) * 1024 + (k0) + scol,                            \
                (const char*)(Bs[buf] + (2 * wid + i_) * 512));                         \
    } } while (0)

    f32x4 acc[4][4] = {};
    GSTAGE(0, 0);

    for (int k0 = 0; k0 < 1024; k0 += 32) {
        const int buf = (k0 >> 5) & 1;
        __syncthreads();                       // drains vmcnt(0): buf landed, other buf free
        if (k0 + 32 < 1024) GSTAGE(buf ^ 1, k0 + 32);
        bf16x8 af[4], bf[4];
#pragma unroll
        for (int mi = 0; mi < 4; ++mi) {
            int row = wr + mi * 16 + l15;
            af[mi] = *(const bf16x8*)(As[buf] + row * 32 + ((lk ^ (row & 3)) << 3));
        }
#pragma unroll
        for (int ni = 0; ni < 4; ++ni) {
            int row = wc + ni * 16 + l15;
            bf[ni] = *(const bf16x8*)(Bs[buf] + row * 32 + ((lk ^ (row & 3)) << 3));
        }
        __builtin_amdgcn_s_setprio(1);
#pragma unroll
        for (int mi = 0; mi < 4; ++mi)
#pragma unroll
            for (int ni = 0; ni < 4; ++ni)
                acc[mi][ni] = __builtin_amdgcn_mfma_f32_16x16x32_bf16(af[mi], bf[ni], acc[mi][ni], 0, 0, 0);
        __builtin_amdgcn_s_setprio(0);
    }
#undef GSTAGE

    // epilogue; C/D layout: col = lane&15, row = (lane>>4)*4 + r
#pragma unroll
    for (int mi = 0; mi < 4; ++mi)
#pragma unroll
        for (int ni = 0; ni < 4; ++ni)
#pragma unroll
            for (int r = 0; r < 4; ++r) {
                int row = m0 + wr + mi * 16 + lk * 4 + r;
                int col = n0 + wc + ni * 16 + l15;
                float v = acc[mi][ni][r];
                if (MODE == 0) {
                    if (col < 1024) {            // Q: (+bq +pe) * QSCALE (base-2 domain)
                        v = (v + bq[col] + pe[row * HDIM + (col & 127)]) * QSCALE;
                        Qb[(long)row * 1024 + col] = f2bf(v);
                    } else if (col < 1152) {     // K: +bkv[0:128] +pe
                        int d = col - 1024;
                        v += bkv[d] + pe[row * HDIM + d];
                        Kb[row * HDIM + d] = f2bf(v);
                    } else {                     // V: +bkv[128:256], transposed [d][t]
                        v += bkv[col - 1024];
                        Vtb[(long)(col - 1152) * T_LEN + row] = f2bf(v);
                    }
                } else {
                    Cout[(long)row * 1024 + col] = v;
                }
            }
}

// multi-piece base index for row j (j>=8): pieces before row j among multi-piece rows
__device__ __forceinline__ int mbase(int j) {
    return (j < 16) ? (j - 8) * 2 : (j < 24) ? 16 + (j - 16) * 3 : 40 + (j - 24) * 4;
}

// ---------------- flash attention v6: uniform 16-tile pieces ----------------
// 640 blocks: each (q-tile j, head) row of L=2j+2 key-tiles is cut into ceil(L/16)
// pieces of <=16 tiles. Single-piece rows (j<8) write direct; multi-piece rows write
// bf16 partials + (m,l), merged by combine_kernel. Longest pieces dispatched first.
__global__ __launch_bounds__(256, 2)
void attn_kernel(const short* __restrict__ Qb, const short* __restrict__ Kb,
                 const short* __restrict__ Vtb, short* __restrict__ Ob,
                 short* __restrict__ opA, short* __restrict__ opB,
                 float* __restrict__ ml) {
    const int tid = threadIdx.x, lane = tid & 63, w = tid >> 6;
    const int q31 = lane & 31, hi = lane >> 5;

    const int bx = blockIdx.x;
    const int q = 79 - (bx >> 3);              // per-head piece id, long rows first
    const int h = bx & 7;
    int g, rr;
    if (q < 8)       { g = 0; rr = q; }
    else if (q < 24) { g = 1; rr = q - 8; }
    else if (q < 48) { g = 2; rr = q - 24; }
    else             { g = 3; rr = q - 48; }
    const int P = g + 1;                       // pieces in this row
    const int j = g * 8 + rr / P;
    const int p = rr % P;
    const int L = 2 * j + 2;
    const int t0 = p * 16;
    const int tend = (t0 + 16 < L) ? t0 + 16 : L;
    const bool last = (p == P - 1);
    const int mask_from = last ? 2 * j : 0x7fffffff;   // only tiles 2j,2j+1 need masking
    const int qw = j * 128 + w * 32;

    __shared__ __align__(16) char Ks[2][64 * 256];     // K [key][d] bf16, chunk-swizzled
    __shared__ __align__(16) char Vts[2][128 * 128];   // V^T [d][key] bf16, chunk-swizzled

    // Q B-frags: col = q31 = query, k = kc*16 + hi*8 + jj. Pre-scaled by QSCALE.
    bf16x8 qf[8];
#pragma unroll
    for (int kc = 0; kc < 8; ++kc)
        qf[kc] = *(const bf16x8*)(Qb + (long)(qw + q31) * 1024 + h * HDIM + kc * 16 + hi * 8);

    f32x16 o[4] = {};
    float m2 = -INFINITY, lsum = 0.f;
    const int swz = (q31 & 7) << 4;

#define STAGE(buf, kbase) do {                                                          \
    _Pragma("unroll") for (int i_ = 0; i_ < 4; ++i_) {                                  \
        int id_ = (w * 4 + i_) * 64 + lane;                                             \
        int ky_ = id_ >> 4, kc_ = id_ & 15;                                             \
        gload16(Kb + (long)((kbase) + ky_) * HDIM + ((kc_ ^ (ky_ & 7)) * 8),            \
                Ks[buf] + (w * 4 + i_) * 1024);                                         \
        int d_ = id_ >> 3, vc_ = id_ & 7;                                               \
        gload16(Vtb + (long)d_ * T_LEN + (kbase) + ((vc_ ^ (d_ & 7)) * 8),              \
                Vts[buf] + (w * 4 + i_) * 1024);                                        \
    } } while (0)

    STAGE(0, t0 * 64);

    for (int t = t0; t < tend; ++t) {
        const int cur = (t - t0) & 1;
        __syncthreads();                       // vmcnt(0) drain: tile t landed
        if (t + 1 < tend) STAGE(cur ^ 1, (t + 1) * 64);

        // S^T = K @ Q^T : col = q31 = query, row = crow(r,hi) = (r&3)+8*(r>>2)+4*hi
        const char* Kbuf = Ks[cur];
        f32x16 S0 = {}, S1 = {};
        __builtin_amdgcn_s_setprio(1);
#pragma unroll
        for (int kc = 0; kc < 8; ++kc) {
            bf16x8 a0 = *(const bf16x8*)(Kbuf + q31 * 256 + ((kc * 32 + hi * 16) ^ swz));
            bf16x8 a1 = *(const bf16x8*)(Kbuf + (32 + q31) * 256 + ((kc * 32 + hi * 16) ^ swz));
            S0 = __builtin_amdgcn_mfma_f32_32x32x16_bf16(a0, qf[kc], S0, 0, 0, 0);
            S1 = __builtin_amdgcn_mfma_f32_32x32x16_bf16(a1, qf[kc], S1, 0, 0, 0);
        }
        __builtin_amdgcn_s_setprio(0);

        if (t >= mask_from) {
            const int query = qw + q31, kb = t * 64 + 4 * hi;
#pragma unroll
            for (int r = 0; r < 16; ++r) {
                int krow = kb + (r & 3) + 8 * (r >> 2);
                if (krow > query)      S0[r] = -1e30f;
                if (krow + 32 > query) S1[r] = -1e30f;
            }
        }

        // defer-max online softmax (base-2); lane owns query q31
        float pmax = fmaxf(S0[0], S1[0]);
#pragma unroll
        for (int r = 1; r < 16; ++r) pmax = fmaxf(pmax, fmaxf(S0[r], S1[r]));
        if (!__all(pmax <= m2 + 8.f)) {
            float tm = fmaxf(pmax, __shfl_xor(pmax, 32));
            float nm = fmaxf(m2, tm);
            float sc = __builtin_amdgcn_exp2f(m2 - nm);
            m2 = nm;
            lsum *= sc;
#pragma unroll
            for (int r = 0; r < 16; ++r) {
                float scr = __shfl(sc, (r & 3) + 8 * (r >> 2) + 4 * hi);
                o[0][r] *= scr; o[1][r] *= scr; o[2][r] *= scr; o[3][r] *= scr;
            }
        }

        unsigned pw0[8], pw1[8];
#pragma unroll
        for (int i = 0; i < 8; ++i) {
            float e0 = __builtin_amdgcn_exp2f(S0[2 * i] - m2);
            float e1 = __builtin_amdgcn_exp2f(S0[2 * i + 1] - m2);
            float f0 = __builtin_amdgcn_exp2f(S1[2 * i] - m2);
            float f1 = __builtin_amdgcn_exp2f(S1[2 * i + 1] - m2);
            lsum += (e0 + e1) + (f0 + f1);
            pw0[i] = cvt_pk_bf16(e0, e1);
            pw1[i] = cvt_pk_bf16(f0, f1);
        }
        plswap(pw0[0], pw0[2]); plswap(pw0[1], pw0[3]);
        plswap(pw0[4], pw0[6]); plswap(pw0[5], pw0[7]);
        plswap(pw1[0], pw1[2]); plswap(pw1[1], pw1[3]);
        plswap(pw1[4], pw1[6]); plswap(pw1[5], pw1[7]);
        bf16x8 pfr[4];
        pfr[0] = mk8(pw0[0], pw0[1], pw0[2], pw0[3]);
        pfr[1] = mk8(pw0[4], pw0[5], pw0[6], pw0[7]);
        pfr[2] = mk8(pw1[0], pw1[1], pw1[2], pw1[3]);
        pfr[3] = mk8(pw1[4], pw1[5], pw1[6], pw1[7]);

        // O += P @ V
        const char* Vbuf = Vts[cur];
        __builtin_amdgcn_s_setprio(1);
#pragma unroll
        for (int ks = 0; ks < 4; ++ks)
#pragma unroll
            for (int dt = 0; dt < 4; ++dt) {
                bf16x8 vb = *(const bf16x8*)(Vbuf + (dt * 32 + q31) * 128 + ((ks * 32 + hi * 16) ^ swz));
                o[dt] = __builtin_amdgcn_mfma_f32_32x32x16_bf16(pfr[ks], vb, o[dt], 0, 0, 0);
            }
        __builtin_amdgcn_s_setprio(0);
    }
#undef STAGE

    lsum += __shfl_xor(lsum, 32);              // merge the two key-halves

    if (P == 1) {                              // single piece: normalize + write direct
        float inv = 1.f / lsum;
#pragma unroll
        for (int r = 0; r < 16; ++r) {
            int qrow = (r & 3) + 8 * (r >> 2) + 4 * hi;
            float rl = __shfl(inv, qrow);
            short* dst = Ob + (long)(qw + qrow) * 1024 + h * HDIM + q31;
            dst[0]  = f2bf(o[0][r] * rl);
            dst[32] = f2bf(o[1][r] * rl);
            dst[64] = f2bf(o[2][r] * rl);
            dst[96] = f2bf(o[3][r] * rl);
        }
    } else {                                   // bf16 partial + (m,l)
        const int pidx = (mbase(j) + p) * 8 + h;
        short* Op = (pidx < 384) ? (opA + (long)pidx * 16384)
                                 : (opB + (long)(pidx - 384) * 16384);
#pragma unroll
        for (int r = 0; r < 16; ++r) {
            int qrow = (r & 3) + 8 * (r >> 2) + 4 * hi;
            short* dst = Op + (w * 32 + qrow) * 128 + q31;
            dst[0]  = f2bf(o[0][r]);
            dst[32] = f2bf(o[1][r]);
            dst[64] = f2bf(o[2][r]);
            dst[96] = f2bf(o[3][r]);
        }
        if (hi == 0) {
            float* mlp = ml + ((long)pidx * 128 + w * 32 + q31) * 2;
            mlp[0] = m2; mlp[1] = lsum;
        }
    }
}

// ---------------- combine: merge the P<=4 key-range partials of each multi-piece row ----------------
__global__ __launch_bounds__(256)
void combine_kernel(const short* __restrict__ opA, const short* __restrict__ opB,
                    const float* __restrict__ ml, short* __restrict__ Ob) {
    const int bz = blockIdx.x;                 // 0..191
    const int j = 8 + (bz >> 3), h = bz & 7;
    const int P = (j >> 3) + 1;
    const int mb = mbase(j);
    const int qq = threadIdx.x >> 1, dh = (threadIdx.x & 1) * 64;

    float m = -INFINITY, l = 0.f;
    float acc[64];
#pragma unroll
    for (int d = 0; d < 64; ++d) acc[d] = 0.f;

    for (int p = 0; p < P; ++p) {
        const int pidx = (mb + p) * 8 + h;
        const float* mlp = ml + ((long)pidx * 128 + qq) * 2;
        float mp = mlp[0], lp = mlp[1];
        float nm = fmaxf(m, mp);
        float cA = __builtin_amdgcn_exp2f(m - nm);
        float cB = __builtin_amdgcn_exp2f(mp - nm);
        m = nm;
        l = l * cA + lp * cB;
        const short* Os = ((pidx < 384) ? (opA + (long)pidx * 16384)
                                        : (opB + (long)(pidx - 384) * 16384))
                          + qq * 128 + dh;
#pragma unroll
        for (int c = 0; c < 8; ++c) {
            bf16x8 v = *(const bf16x8*)(Os + c * 8);
#pragma unroll
            for (int e = 0; e < 8; ++e)
                acc[c * 8 + e] = acc[c * 8 + e] * cA + bf2f(v[e]) * cB;
        }
    }
    float inv = 1.f / l;
    short* dst = Ob + (long)(j * 128 + qq) * 1024 + h * HDIM + dh;
#pragma unroll
    for (int c = 0; c < 16; ++c) {
        s16x4 r;
#pragma unroll
        for (int e = 0; e < 4; ++e) r[e] = f2bf(acc[c * 4 + e] * inv);
        *(s16x4*)(dst + c * 4) = r;
    }
}

extern "C" void kernel_launch(void* const* d_in, const int* in_sizes, int n_in,
                              void* d_out, int out_size, void* d_ws, size_t ws_size,
                              hipStream_t stream) {
    const float* x   = (const float*)d_in[0];
    const float* Wq  = (const float*)d_in[1];
    const float* bq  = (const float*)d_in[2];
    const float* Wkv = (const float*)d_in[3];
    const float* bkv = (const float*)d_in[4];
    const float* Wo  = (const float*)d_in[5];
    float* out = (float*)d_out;
    char* ws = (char*)d_ws;

    float* pe   = (float*)(ws);                       // [0, 2MB)
    short* xb   = (short*)(ws + (2l  << 20));         // [2, 10)
    short* wt   = (short*)(ws + (10l << 20));         // [10, 12.5)  (W^T: [n][k])
    short* wot  = (short*)(ws + (13l << 20));         // [13, 15)    (Wo^T)
    short* Qb   = (short*)(ws + (15l << 20));         // [15, 23)
    short* Kb   = (short*)(ws + (23l << 20));         // [23, 24)
    short* Vtb  = (short*)(ws + (24l << 20));         // [24, 25)
    short* Ab   = (short*)(ws + (25l << 20));         // [25, 33)
    // partials: regionA overlays pe/xb/wt (dead after gemm<0>); regionB + ml beyond Ab
    short* opA  = (short*)(ws);                       // pieces 0..383   (12MB, stream-safe overlay)
    short* opB  = (short*)(ws + (33l << 20));         // pieces 384..575 (6MB)
    float* ml   = (float*)(ws + (39l << 20));         // 576KB

    pe_kernel<<<1024, 256, 0, stream>>>(pe);
    cvt_kernel<<<4096, 256, 0, stream>>>(x, xb, T_LEN * EMB);
    transpose_cvt_kernel<<<dim3(32, 32), 256, 0, stream>>>(Wq,  wt,               EMB, 1024);
    transpose_cvt_kernel<<<dim3(32, 8),  256, 0, stream>>>(Wkv, wt + 1024 * 1024, EMB, 256);
    transpose_cvt_kernel<<<dim3(32, 32), 256, 0, stream>>>(Wo,  wot,              EMB, 1024);

    gemm_kernel<0><<<dim3(32, 10), 256, 0, stream>>>(xb, wt, bq, bkv, pe,
                                                     Qb, Kb, Vtb, nullptr);
    attn_kernel<<<640, 256, 0, stream>>>(Qb, Kb, Vtb, Ab, opA, opB, ml);
    combine_kernel<<<192, 256, 0, stream>>>(opA, opB, ml, Ab);
    gemm_kernel<1><<<dim3(32, 8), 256, 0, stream>>>(Ab, wot, nullptr, nullptr, nullptr,
                                                    nullptr, nullptr, nullptr, out);
}